// Round 7
// baseline (991.498 us; speedup 1.0000x reference)
//
#include <hip/hip_runtime.h>
#include <math.h>

// SegmentalLM forward. V=4000 E=H=256 M=128 B=32 L=4, S=126, NROW=5*4032=20160.
//
// R3: encoder 1 block/batch (no cross-block sync; R2: ~10us/step handshake).
// R4: logits -> f16 MFMA + fused exp-sum (constant shift).
// R5: all dense GEMMs -> f16 MFMA.
// R6: fused decoder step; logits 2 vocab halves; waves_per_eu(2,2) (failed:
//     VGPR stayed 128 -> LLVM REMATERIALIZES invariant weight loads).
// R7: (a) asm-opaque pin on encoder weight registers (defeats remat; 26 of 32
//     uint4/row in VGPR, 6 in LDS -> zero per-step L2 weight stream).
//     (b) encoder Xg in f16 (halves enc HBM fetch).

#define LOGNEG -1000000.0f
#define GF_BIAS 1
#define GF_TANH 2
#define GF_F16OUT 16
#define ZSHIFT 8.0f

typedef unsigned int uint32;
typedef _Float16 half2_t __attribute__((ext_vector_type(2)));
typedef _Float16 half8_t __attribute__((ext_vector_type(8)));
typedef float    f32x4_t __attribute__((ext_vector_type(4)));

__device__ __forceinline__ float sigmf_(float x){ return 1.0f/(1.0f+expf(-x)); }

__device__ __forceinline__ float dot2f(uint32 w, uint32 h, float acc){
#if __has_builtin(__builtin_amdgcn_fdot2)
    return __builtin_amdgcn_fdot2(__builtin_bit_cast(half2_t, w),
                                  __builtin_bit_cast(half2_t, h), acc, false);
#else
    half2_t a = __builtin_bit_cast(half2_t, w);
    half2_t b = __builtin_bit_cast(half2_t, h);
    return acc + (float)a[0]*(float)b[0] + (float)a[1]*(float)b[1];
#endif
}

// ---------------- fused prep: f16 packs + biases ----------------
__global__ __launch_bounds__(256) void k_prep_pack(
    const float* __restrict__ emb, const float* __restrict__ e2v_b,
    const float* __restrict__ eWih, const float* __restrict__ dWih,
    const float* __restrict__ dWhh, const float* __restrict__ eWhh,
    const float* __restrict__ sosW, const float* __restrict__ dhtW,
    const float* __restrict__ ebih, const float* __restrict__ ebhh,
    const float* __restrict__ dbih, const float* __restrict__ dbhh,
    _Float16* __restrict__ emb16, float* __restrict__ biasOff,
    _Float16* __restrict__ eWih16, _Float16* __restrict__ dWih16,
    _Float16* __restrict__ dWhh16, _Float16* __restrict__ eWhh16,
    _Float16* __restrict__ sosW16, _Float16* __restrict__ dhtW16,
    float* __restrict__ bias_e, float* __restrict__ bias_d)
{
    int bx = blockIdx.x, c = threadIdx.x;
    if (bx < 4032){
        int row = bx;
        emb16[(size_t)row*256 + c] = (row < 4000) ? (_Float16)emb[(size_t)row*256 + c] : (_Float16)0.0f;
        if (c == 0) biasOff[row] = (row < 4000) ? (e2v_b[row] - ZSHIFT) : -200.0f;
    } else if (bx < 5056){
        int r = bx - 4032; eWih16[(size_t)r*256 + c] = (_Float16)eWih[(size_t)r*256 + c];
    } else if (bx < 6080){
        int r = bx - 5056; dWih16[(size_t)r*256 + c] = (_Float16)dWih[(size_t)r*256 + c];
    } else if (bx < 7104){
        int r = bx - 6080; dWhh16[(size_t)r*256 + c] = (_Float16)dWhh[(size_t)r*256 + c];
    } else if (bx < 8128){
        int r = bx - 7104; eWhh16[(size_t)r*256 + c] = (_Float16)eWhh[(size_t)r*256 + c];
    } else if (bx < 8384){
        int r = bx - 8128; sosW16[(size_t)r*256 + c] = (_Float16)sosW[(size_t)r*256 + c];
    } else if (bx < 8640){
        int r = bx - 8384; dhtW16[(size_t)r*256 + c] = (_Float16)dhtW[(size_t)r*256 + c];
    } else {
        int j = (bx - 8640)*256 + c;
        if (j < 1024){ bias_e[j] = ebih[j]+ebhh[j]; bias_d[j] = dbih[j]+dbhh[j]; }
    }
}

// ---------------- embed (f16 gather) + is_single ----------------
__global__ __launch_bounds__(256) void k_embed(
    const int* __restrict__ x, const _Float16* __restrict__ emb16,
    _Float16* __restrict__ emb_in16, float* __restrict__ is_s)
{
    int ri = blockIdx.x;
    int m = ri >> 5, b = ri & 31;
    int tok = x[b*128 + m];
    int h = threadIdx.x;
    emb_in16[(size_t)ri*256 + h] = emb16[(size_t)tok*256 + h];
    if (h == 0) is_s[ri] = (tok <= 2) ? LOGNEG : 0.0f;
}

// ---------------- generic f16 MFMA GEMM: C(M,N) = A(M,256) @ W(N,256)^T ----------------
__global__ __launch_bounds__(256) void k_gemm16(
    const _Float16* __restrict__ A, const _Float16* __restrict__ W,
    const float* __restrict__ bias, float* __restrict__ C,
    _Float16* __restrict__ C16, int N, int flags)
{
    __shared__ _Float16 Bs[64*264];
    int tid = threadIdx.x;
    int wave = tid >> 6, lane = tid & 63;
    int ln = lane & 15, quad = lane >> 4;
    int rowBlk = blockIdx.y * 64, colBlk = blockIdx.x * 64;

    #pragma unroll
    for (int i = 0; i < 8; i++){
        int idx = i*256 + tid;
        int row = idx >> 5, c16 = idx & 31;
        *(uint4*)&Bs[row*264 + c16*8] =
            *(const uint4*)(W + (size_t)(colBlk+row)*256 + c16*8);
    }
    half8_t a[8];
    const half8_t* Ap = (const half8_t*)(A + (size_t)(rowBlk + wave*16 + ln)*256 + quad*8);
    #pragma unroll
    for (int ks = 0; ks < 8; ks++) a[ks] = Ap[ks*4];
    __syncthreads();

    #pragma unroll
    for (int ct = 0; ct < 4; ct++){
        f32x4_t c4 = {0.f,0.f,0.f,0.f};
        const _Float16* bp = &Bs[(ct*16+ln)*264 + quad*8];
        #pragma unroll
        for (int ks = 0; ks < 8; ks++){
            half8_t b = *(const half8_t*)(bp + ks*32);
            c4 = __builtin_amdgcn_mfma_f32_16x16x32_f16(a[ks], b, c4, 0, 0, 0);
        }
        int c = colBlk + ct*16 + ln;
        #pragma unroll
        for (int reg = 0; reg < 4; reg++){
            int r = rowBlk + wave*16 + quad*4 + reg;
            float v = c4[reg];
            if (flags & GF_BIAS) v += bias[c];
            if (flags & GF_TANH) v = tanhf(v);
            if (flags & GF_F16OUT) C16[(size_t)r*N + c] = (_Float16)v;
            else                   C  [(size_t)r*N + c] = v;
        }
    }
}

// ---------------- encoder LSTM recurrence ----------------
// 32 blocks x 512 thr, waves_per_eu(2,2) -> 256 VGPR budget. Thread t owns
// gate rows t and t+512. Per row: 26 uint4 of Whh16 (k[0,208)) PINNED in VGPRs
// via opaque asm (R6 showed LLVM rematerializes invariant loads otherwise),
// 6 uint4 (k[208,256)) in LDS. Zero per-step global weight traffic.
// Dyn LDS: 6*1024*16 (w) + 512 (h f16) + 4096 (g) = 102912 B.
__global__ void __attribute__((amdgpu_flat_work_group_size(512,512), amdgpu_waves_per_eu(2,2)))
k_enc_rnn(
    const _Float16* __restrict__ Xg16, const _Float16* __restrict__ Whh16,
    const float* __restrict__ h0, const float* __restrict__ c0,
    _Float16* __restrict__ enc_out16)
{
    extern __shared__ char smem[];
    uint4*  wlds = (uint4*)smem;                   // [6][1024]
    uint32* h_u  = (uint32*)(smem + 98304);        // 128 dwords = 256 f16
    float*  g_s  = (float*)(smem + 98816);         // 1024
    const int b = blockIdx.x, tid = threadIdx.x;
    const int r0 = tid, r1 = tid + 512;

    const uint4* p0 = (const uint4*)(Whh16 + (size_t)r0*256);
    const uint4* p1 = (const uint4*)(Whh16 + (size_t)r1*256);
    uint4 w0[26], w1[26];
    #pragma unroll
    for (int i = 0; i < 26; i++){ w0[i] = p0[i]; w1[i] = p1[i]; }
    // opaque pin: prevent rematerialization of the weight loads
    #pragma unroll
    for (int i = 0; i < 26; i++){
        asm volatile("" : "+v"(w0[i].x), "+v"(w0[i].y), "+v"(w0[i].z), "+v"(w0[i].w));
        asm volatile("" : "+v"(w1[i].x), "+v"(w1[i].y), "+v"(w1[i].z), "+v"(w1[i].w));
    }
    #pragma unroll
    for (int i = 0; i < 6; i++){
        wlds[i*1024 + r0] = p0[26 + i];
        wlds[i*1024 + r1] = p1[26 + i];
    }
    float c = 0.f;
    if (tid < 256){
        c = c0[tid];
        ((_Float16*)h_u)[tid] = (_Float16)h0[tid];
    }
    __syncthreads();
    const uint4* hu4 = (const uint4*)h_u;

    float xg0 = (float)Xg16[(size_t)b*1024 + r0];
    float xg1 = (float)Xg16[(size_t)b*1024 + r1];
    for (int t = 0; t < 128; t++){
        float nxg0 = 0.f, nxg1 = 0.f;
        if (t < 127){
            nxg0 = (float)Xg16[((size_t)((t+1)*32+b))*1024 + r0];
            nxg1 = (float)Xg16[((size_t)((t+1)*32+b))*1024 + r1];
        }
        float a0 = 0.f, a1 = 0.f;
        #pragma unroll
        for (int i = 0; i < 26; i++){
            uint4 hh = hu4[i];
            a0 = dot2f(w0[i].x, hh.x, a0); a0 = dot2f(w0[i].y, hh.y, a0);
            a0 = dot2f(w0[i].z, hh.z, a0); a0 = dot2f(w0[i].w, hh.w, a0);
            a1 = dot2f(w1[i].x, hh.x, a1); a1 = dot2f(w1[i].y, hh.y, a1);
            a1 = dot2f(w1[i].z, hh.z, a1); a1 = dot2f(w1[i].w, hh.w, a1);
        }
        #pragma unroll
        for (int i = 0; i < 6; i++){
            uint4 hh = hu4[26 + i];
            uint4 v0 = wlds[i*1024 + r0];
            uint4 v1 = wlds[i*1024 + r1];
            a0 = dot2f(v0.x, hh.x, a0); a0 = dot2f(v0.y, hh.y, a0);
            a0 = dot2f(v0.z, hh.z, a0); a0 = dot2f(v0.w, hh.w, a0);
            a1 = dot2f(v1.x, hh.x, a1); a1 = dot2f(v1.y, hh.y, a1);
            a1 = dot2f(v1.z, hh.z, a1); a1 = dot2f(v1.w, hh.w, a1);
        }
        g_s[r0] = a0 + xg0;
        g_s[r1] = a1 + xg1;
        __syncthreads();
        if (tid < 256){
            float gi = g_s[tid], gf = g_s[256+tid], gg = g_s[512+tid], go = g_s[768+tid];
            c = sigmf_(gf)*c + sigmf_(gi)*tanhf(gg);
            float hn = sigmf_(go)*tanhf(c);
            enc_out16[((size_t)(t*32+b))*256 + tid] = (_Float16)(0.5f*hn);
            ((_Float16*)h_u)[tid] = (_Float16)hn;
        }
        __syncthreads();
        xg0 = nxg0; xg1 = nxg1;
    }
}

// ---------------- fused decoder step: 4-gate MFMA + base + LSTM pointwise ----------------
__global__ __launch_bounds__(256) void k_dec_step(
    const _Float16* __restrict__ hprev, const _Float16* __restrict__ dWhh16,
    const _Float16* __restrict__ base16, const float* __restrict__ bias_d,
    float* __restrict__ dec_c, _Float16* __restrict__ dec16_j, int jstep)
{
    __shared__ _Float16 Bs[64*264];
    int tid = threadIdx.x;
    int wave = tid >> 6, lane = tid & 63;
    int ln = lane & 15, quad = lane >> 4;
    int u0 = blockIdx.x * 64, r0 = blockIdx.y * 64;

    half8_t a[8];
    const half8_t* Ap = (const half8_t*)(hprev + (size_t)(r0 + wave*16 + ln)*256 + quad*8);
    #pragma unroll
    for (int ks = 0; ks < 8; ks++) a[ks] = Ap[ks*4];

    f32x4_t cg[4][4];
    #pragma unroll
    for (int g = 0; g < 4; g++){
        __syncthreads();
        #pragma unroll
        for (int i = 0; i < 8; i++){
            int idx = i*256 + tid;
            int row = idx >> 5, c16 = idx & 31;
            *(uint4*)&Bs[row*264 + c16*8] =
                *(const uint4*)(dWhh16 + (size_t)(g*256 + u0 + row)*256 + c16*8);
        }
        __syncthreads();
        #pragma unroll
        for (int ct = 0; ct < 4; ct++){
            f32x4_t c4 = {0.f,0.f,0.f,0.f};
            const _Float16* bp = &Bs[(ct*16+ln)*264 + quad*8];
            #pragma unroll
            for (int ks = 0; ks < 8; ks++){
                half8_t b = *(const half8_t*)(bp + ks*32);
                c4 = __builtin_amdgcn_mfma_f32_16x16x32_f16(a[ks], b, c4, 0, 0, 0);
            }
            cg[g][ct] = c4;
        }
    }
    #pragma unroll
    for (int ct = 0; ct < 4; ct++){
        int u = u0 + ct*16 + ln;
        #pragma unroll
        for (int reg = 0; reg < 4; reg++){
            int r = r0 + wave*16 + quad*4 + reg;
            float bi, bf, bg, bo;
            if (jstep == 0){
                const _Float16* bp = base16 + (size_t)r*1024 + u;
                bi = (float)bp[0]; bf = (float)bp[256]; bg = (float)bp[512]; bo = (float)bp[768];
            } else {
                int s = r >> 5, b_ = r & 31;
                int m = s + jstep;
                if (m < 128){
                    const _Float16* bp = base16 + (size_t)(m*32+b_)*1024 + u;
                    bi = (float)bp[0]; bf = (float)bp[256]; bg = (float)bp[512]; bo = (float)bp[768];
                } else {
                    bi = bias_d[u]; bf = bias_d[256+u]; bg = bias_d[512+u]; bo = bias_d[768+u];
                }
            }
            float gi = cg[0][ct][reg] + bi;
            float gf = cg[1][ct][reg] + bf;
            float gg = cg[2][ct][reg] + bg;
            float go = cg[3][ct][reg] + bo;
            float cv = (jstep == 0) ? 0.0f : dec_c[(size_t)r*256 + u];
            cv = sigmf_(gf)*cv + sigmf_(gi)*tanhf(gg);
            float hv = sigmf_(go)*tanhf(cv);
            dec_c[(size_t)r*256 + u] = cv;
            dec16_j[(size_t)r*256 + u] = (_Float16)hv;
        }
    }
}

// ---------------- logits: f16 MFMA GEMM + fused exp-sum (2 vocab halves) ----------------
__global__ __launch_bounds__(256) void k_logits(
    const _Float16* __restrict__ dec16, const _Float16* __restrict__ emb16,
    const float* __restrict__ biasOff, float* __restrict__ ps)
{
    __shared__ _Float16 Bs[64*264];
    int tid = threadIdx.x;
    int wave = tid >> 6, lane = tid & 63;
    int ln = lane & 15, quad = lane >> 4;
    int r0 = blockIdx.x * 64;
    int hf = blockIdx.y;
    int vt0 = hf ? 32 : 0, vt1 = hf ? 63 : 32;

    half8_t a[8];
    const half8_t* Ap = (const half8_t*)(dec16 + (size_t)(r0 + wave*16 + ln)*256 + quad*8);
    #pragma unroll
    for (int ks = 0; ks < 8; ks++) a[ks] = Ap[ks*4];

    float s[4] = {0.f,0.f,0.f,0.f};

    for (int vt = vt0; vt < vt1; vt++){
        int v0 = vt*64;
        __syncthreads();
        #pragma unroll
        for (int i = 0; i < 8; i++){
            int idx = i*256 + tid;
            int row = idx >> 5, c16 = idx & 31;
            *(uint4*)&Bs[row*264 + c16*8] =
                *(const uint4*)(emb16 + (size_t)(v0+row)*256 + c16*8);
        }
        __syncthreads();

        #pragma unroll
        for (int ct = 0; ct < 4; ct++){
            f32x4_t c4 = {0.f,0.f,0.f,0.f};
            const _Float16* bp = &Bs[(ct*16+ln)*264 + quad*8];
            #pragma unroll
            for (int ks = 0; ks < 8; ks++){
                half8_t b = *(const half8_t*)(bp + ks*32);
                c4 = __builtin_amdgcn_mfma_f32_16x16x32_f16(a[ks], b, c4, 0, 0, 0);
            }
            float bb = biasOff[v0 + ct*16 + ln];
            #pragma unroll
            for (int reg = 0; reg < 4; reg++)
                s[reg] += __expf(c4[reg] + bb);
        }
    }
    #pragma unroll
    for (int reg = 0; reg < 4; reg++){
        float v = s[reg];
        #pragma unroll
        for (int off = 1; off < 16; off <<= 1) v += __shfl_xor(v, off, 64);
        s[reg] = v;
    }
    if (ln == 0){
        #pragma unroll
        for (int reg = 0; reg < 4; reg++)
            ps[hf*20160 + r0 + wave*16 + quad*4 + reg] = s[reg];
    }
}

// ---------------- extract z[tgt], z[EOS] -> tlp / eosb ----------------
__global__ __launch_bounds__(256) void k_extract(
    const _Float16* __restrict__ dec16, const _Float16* __restrict__ emb16,
    const float* __restrict__ biasOff, const int* __restrict__ x,
    const float* __restrict__ ps,
    float* __restrict__ tlp, float* __restrict__ eosb)
{
    int tid = threadIdx.x;
    int wave = tid >> 6, lane = tid & 63;
    int r = blockIdx.x*4 + wave;            // < 20160
    int t = r / 4032, sb = r % 4032;
    int s_ = sb >> 5, b = sb & 31;
    int m = s_ + 1 + t;
    int tg = (m < 128) ? x[b*128 + m] : 0;

    const uint32* dp = (const uint32*)(dec16 + (size_t)r*256) + lane*2;
    const uint32* ep = (const uint32*)(emb16 + (size_t)tg*256) + lane*2;
    const uint32* zp = (const uint32*)(emb16 + (size_t)3*256) + lane*2;
    uint32 d0 = dp[0], d1 = dp[1];
    float zt = dot2f(d1, ep[1], dot2f(d0, ep[0], 0.f));
    float ze = dot2f(d1, zp[1], dot2f(d0, zp[0], 0.f));
    #pragma unroll
    for (int off = 1; off < 64; off <<= 1){
        zt += __shfl_xor(zt, off, 64);
        ze += __shfl_xor(ze, off, 64);
    }
    if (lane == 0){
        float lse = __logf(ps[r] + ps[20160 + r]);
        zt += biasOff[tg];
        ze += biasOff[3];
        if (t < 4)  tlp[(t*126+s_)*32 + b]      = zt - lse;
        if (t >= 1) eosb[((t-1)*126+s_)*32 + b] = ze - lse;
    }
}

// ---------------- segmental DP + final reduction ----------------
__global__ __launch_bounds__(128) void k_finalize(
    const float* __restrict__ tlp, const float* __restrict__ eosb,
    const float* __restrict__ is_s, const int* __restrict__ lengths,
    float* __restrict__ seg_g, float* __restrict__ out)
{
    int tid = threadIdx.x;
    int k = tid >> 5, b = tid & 31;
    for (int s = 0; s < 126; s++){
        float cum = 0.f;
        for (int kk = 0; kk <= k; kk++) cum += tlp[(kk*126+s)*32 + b];
        if (k >= 1){
            for (int kk = 1; kk <= k; kk++){
                int m = s+1+kk;
                if (m < 128) cum += is_s[m*32+b];
            }
            cum += is_s[(s+1)*32 + b];
        }
        float lp = cum + eosb[(k*126+s)*32 + b];
        int jl = min(4, 126 - s);
        if (k >= jl) lp = LOGNEG;
        seg_g[(s*4+k)*32 + b] = lp;
    }
    __threadfence_block();
    __syncthreads();
    __shared__ float nll_s[32];
    if (tid < 32){
        int target = lengths[tid] - 2;
        float b0 = 0.f, b1 = LOGNEG, b2 = LOGNEG, b3 = LOGNEG;
        float nllb = 0.f;
        for (int e = 1; e <= 126; e++){
            float v0 = b0 + seg_g[((e-1)*4+0)*32 + tid];
            float v1 = b1 + ((e >= 2) ? seg_g[((e-2)*4+1)*32 + tid] : LOGNEG);
            float v2 = b2 + ((e >= 3) ? seg_g[((e-3)*4+2)*32 + tid] : LOGNEG);
            float v3 = b3 + ((e >= 4) ? seg_g[((e-4)*4+3)*32 + tid] : LOGNEG);
            float mx = fmaxf(fmaxf(v0,v1), fmaxf(v2,v3));
            float a = mx + logf(expf(v0-mx)+expf(v1-mx)+expf(v2-mx)+expf(v3-mx));
            if (e == target) nllb = -a;
            b3 = b2; b2 = b1; b1 = b0; b0 = a;
        }
        nll_s[tid] = nllb;
    }
    __syncthreads();
    if (tid == 0){
        float tot = 0.f; int lsum = 0;
        for (int i = 0; i < 32; i++){ tot += nll_s[i]; lsum += lengths[i]; }
        out[0] = tot / (float)(lsum - 64);
    }
}

extern "C" void kernel_launch(void* const* d_in, const int* in_sizes, int n_in,
                              void* d_out, int out_size, void* d_ws, size_t ws_size,
                              hipStream_t stream)
{
    const int*   x        = (const int*)  d_in[0];
    const int*   lengths  = (const int*)  d_in[1];
    const float* emb      = (const float*)d_in[2];
    const float* e2v_b    = (const float*)d_in[3];
    const float* enc_Wih  = (const float*)d_in[4];
    const float* enc_Whh  = (const float*)d_in[5];
    const float* enc_bih  = (const float*)d_in[6];
    const float* enc_bhh  = (const float*)d_in[7];
    const float* enc_h0   = (const float*)d_in[8];
    const float* enc_c0   = (const float*)d_in[9];
    const float* dec_Wih  = (const float*)d_in[10];
    const float* dec_Whh  = (const float*)d_in[11];
    const float* dec_bih  = (const float*)d_in[12];
    const float* dec_bhh  = (const float*)d_in[13];
    const float* dht_W    = (const float*)d_in[14];
    const float* dht_b    = (const float*)d_in[15];
    const float* sos_W    = (const float*)d_in[16];
    const float* sos_b    = (const float*)d_in[17];
    float* out = (float*)d_out;

    char* wsb = (char*)d_ws;
    size_t off = 0;
    auto alloc = [&](size_t bytes)->void*{
        void* p = (void*)(wsb + off);
        off += ((bytes + 255)/256)*256;
        return p;
    };
    _Float16* emb_in16 = (_Float16*)alloc((size_t)4096*256*2);
    float*    is_s     = (float*)alloc(4096*4);
    _Float16* XgE16    = (_Float16*)alloc((size_t)4096*1024*2);
    _Float16* Xg16     = (_Float16*)alloc((size_t)4096*1024*2);
    _Float16* gb16     = (_Float16*)alloc((size_t)4032*1024*2);
    _Float16* enc_out16= (_Float16*)alloc((size_t)4096*256*2);
    _Float16* sos16    = (_Float16*)alloc((size_t)4032*256*2);
    _Float16* dech0_16 = (_Float16*)alloc((size_t)4032*256*2);
    float*    dec_c    = (float*)alloc((size_t)4032*256*4);
    _Float16* dec16    = (_Float16*)alloc((size_t)5*4032*256*2);
    float*    bias_e   = (float*)alloc(1024*4);
    float*    bias_d   = (float*)alloc(1024*4);
    _Float16* emb16    = (_Float16*)alloc((size_t)4032*256*2);
    float*    biasOff  = (float*)alloc(4032*4);
    float*    ps       = (float*)alloc((size_t)2*20160*4);
    float*    tlp      = (float*)alloc((size_t)4*126*32*4);
    float*    eosb     = (float*)alloc((size_t)4*126*32*4);
    float*    seg_g    = (float*)alloc((size_t)126*4*32*4);
    _Float16* eWih16   = (_Float16*)alloc((size_t)1024*256*2);
    _Float16* dWih16   = (_Float16*)alloc((size_t)1024*256*2);
    _Float16* dWhh16   = (_Float16*)alloc((size_t)1024*256*2);
    _Float16* eWhh16   = (_Float16*)alloc((size_t)1024*256*2);
    _Float16* sosW16   = (_Float16*)alloc((size_t)256*256*2);
    _Float16* dhtW16   = (_Float16*)alloc((size_t)256*256*2);
    (void)ws_size; (void)in_sizes; (void)n_in; (void)out_size;

    hipFuncSetAttribute(reinterpret_cast<const void*>(k_enc_rnn),
                        hipFuncAttributeMaxDynamicSharedMemorySize, 102912);

    // 1. fused prep (f16 packs + bias sums)
    k_prep_pack<<<8644, 256, 0, stream>>>(emb, e2v_b, enc_Wih, dec_Wih, dec_Whh, enc_Whh,
        sos_W, dht_W, enc_bih, enc_bhh, dec_bih, dec_bhh,
        emb16, biasOff, eWih16, dWih16, dWhh16, eWhh16, sosW16, dhtW16, bias_e, bias_d);
    // 2. embeddings + is_single
    k_embed<<<4096, 256, 0, stream>>>(x, emb16, emb_in16, is_s);
    // 3. encoder input-side gates (f16 out)
    k_gemm16<<<dim3(16,64), 256, 0, stream>>>(emb_in16, eWih16, bias_e, nullptr, XgE16,
        1024, GF_BIAS|GF_F16OUT);
    // 4. encoder recurrence (asm-pinned VGPR weights + LDS slice)
    k_enc_rnn<<<32, 512, 102912, stream>>>(XgE16, eWhh16, enc_h0, enc_c0, enc_out16);
    // 5/6. sos16 + dec_h0_16
    k_gemm16<<<dim3(4,63), 256, 0, stream>>>(enc_out16, sosW16, sos_b, nullptr, sos16,
        256, GF_BIAS|GF_F16OUT);
    k_gemm16<<<dim3(4,63), 256, 0, stream>>>(enc_out16, dhtW16, dht_b, nullptr, dech0_16,
        256, GF_BIAS|GF_TANH|GF_F16OUT);
    // 7. gb16 = sos16 @ dWih16^T + bias_d (f16)
    k_gemm16<<<dim3(16,63), 256, 0, stream>>>(sos16, dWih16, bias_d, nullptr, gb16,
        1024, GF_BIAS|GF_F16OUT);
    // 8. Xg16 = emb_in16 @ dWih16^T + bias_d (f16)
    k_gemm16<<<dim3(16,64), 256, 0, stream>>>(emb_in16, dWih16, bias_d, nullptr, Xg16,
        1024, GF_BIAS|GF_F16OUT);
    // 9. decoder recurrence: 5 fused steps
    for (int j = 0; j < 5; j++){
        const _Float16* hA = (j == 0) ? dech0_16 : (dec16 + (size_t)(j-1)*4032*256);
        const _Float16* base = (j == 0) ? gb16 : Xg16;
        k_dec_step<<<dim3(4,63), 256, 0, stream>>>(hA, dWhh16, base, bias_d,
            dec_c, dec16 + (size_t)j*4032*256, j);
    }
    // 10. MFMA logits + fused exp-sum (2 vocab halves)
    k_logits<<<dim3(315,2), 256, 0, stream>>>(dec16, emb16, biasOff, ps);
    // 11. tgt/EOS extraction (combines halves)
    k_extract<<<5040, 256, 0, stream>>>(dec16, emb16, biasOff, x, ps, tlp, eosb);
    // 12. segmental DP + reduction
    k_finalize<<<1, 128, 0, stream>>>(tlp, eosb, is_s, lengths, seg_g, out);
}

// Round 8
// 829.019 us; speedup vs baseline: 1.1960x; 1.1960x over previous
//
#include <hip/hip_runtime.h>
#include <math.h>

// SegmentalLM forward. V=4000 E=H=256 M=128 B=32 L=4, S=126, NROW=5*4032=20160.
//
// R3: encoder 1 block/batch (no cross-block sync; R2: ~10us/step handshake).
// R4/R5: all GEMMs f16 MFMA; logits fused exp-sum (constant shift ZSHIFT).
// R6: fused decoder step. R7 FAILED: asm-pinned weights -> scratch spill
//     (allocator hard-caps this kernel at 128 VGPR; stop fighting it).
// R8: encoder reverted to remat/stream form (9 LDS slots, Xg f16) + the
//     independent decoder input-gate GEMM fused into the encoder launch
//     (runs on the 224 idle CUs); logits in 4 vocab quarters with inline
//     tgt/EOS extraction; head GEMMs merged; embed merged into prep.

#define LOGNEG -1000000.0f
#define GF_BIAS 1
#define GF_TANH 2
#define GF_F16OUT 16
#define ZSHIFT 8.0f

typedef unsigned int uint32;
typedef _Float16 half2_t __attribute__((ext_vector_type(2)));
typedef _Float16 half8_t __attribute__((ext_vector_type(8)));
typedef float    f32x4_t __attribute__((ext_vector_type(4)));

__device__ __forceinline__ float sigmf_(float x){ return 1.0f/(1.0f+expf(-x)); }

__device__ __forceinline__ float dot2f(uint32 w, uint32 h, float acc){
#if __has_builtin(__builtin_amdgcn_fdot2)
    return __builtin_amdgcn_fdot2(__builtin_bit_cast(half2_t, w),
                                  __builtin_bit_cast(half2_t, h), acc, false);
#else
    half2_t a = __builtin_bit_cast(half2_t, w);
    half2_t b = __builtin_bit_cast(half2_t, h);
    return acc + (float)a[0]*(float)b[0] + (float)a[1]*(float)b[1];
#endif
}

// ---- shared 64x64 f16 MFMA GEMM tile body (Bs provided by caller) ----
// All threads of the block must call (contains __syncthreads); threads >=256 idle.
__device__ __forceinline__ void gemm16_body(
    _Float16* Bs, int tid,
    const _Float16* __restrict__ A, const _Float16* __restrict__ W,
    const float* __restrict__ bias, float* __restrict__ C,
    _Float16* __restrict__ C16, int N, int flags, int rowBlk, int colBlk)
{
    int wave = tid >> 6, lane = tid & 63;
    int ln = lane & 15, quad = lane >> 4;
    half8_t a[8];
    if (tid < 256){
        #pragma unroll
        for (int i = 0; i < 8; i++){
            int idx = i*256 + tid;
            int row = idx >> 5, c16 = idx & 31;
            *(uint4*)&Bs[row*264 + c16*8] =
                *(const uint4*)(W + (size_t)(colBlk+row)*256 + c16*8);
        }
        const half8_t* Ap = (const half8_t*)(A + (size_t)(rowBlk + wave*16 + ln)*256 + quad*8);
        #pragma unroll
        for (int ks = 0; ks < 8; ks++) a[ks] = Ap[ks*4];
    }
    __syncthreads();
    if (tid < 256){
        #pragma unroll
        for (int ct = 0; ct < 4; ct++){
            f32x4_t c4 = {0.f,0.f,0.f,0.f};
            const _Float16* bp = &Bs[(ct*16+ln)*264 + quad*8];
            #pragma unroll
            for (int ks = 0; ks < 8; ks++){
                half8_t b = *(const half8_t*)(bp + ks*32);
                c4 = __builtin_amdgcn_mfma_f32_16x16x32_f16(a[ks], b, c4, 0, 0, 0);
            }
            int c = colBlk + ct*16 + ln;
            #pragma unroll
            for (int reg = 0; reg < 4; reg++){
                int r = rowBlk + wave*16 + quad*4 + reg;
                float v = c4[reg];
                if (flags & GF_BIAS) v += bias[c];
                if (flags & GF_TANH) v = tanhf(v);
                if (flags & GF_F16OUT) C16[(size_t)r*N + c] = (_Float16)v;
                else                   C  [(size_t)r*N + c] = v;
            }
        }
    }
}

// ---------------- fused prep: f16 packs + biases + embed gather ----------------
// 0..4031 emb16+biasOff | 4032..5055 eWih16 | 5056..6079 dWih16 | 6080..7103 dWhh16
// 7104..8127 eWhh16 | 8128..8383 sosW16 | 8384..8639 dhtW16 | 8640..8643 biases
// 8644..12739 embed gather (from f32 emb; independent of emb16 writes)
__global__ __launch_bounds__(256) void k_prep_pack(
    const int* __restrict__ x,
    const float* __restrict__ emb, const float* __restrict__ e2v_b,
    const float* __restrict__ eWih, const float* __restrict__ dWih,
    const float* __restrict__ dWhh, const float* __restrict__ eWhh,
    const float* __restrict__ sosW, const float* __restrict__ dhtW,
    const float* __restrict__ ebih, const float* __restrict__ ebhh,
    const float* __restrict__ dbih, const float* __restrict__ dbhh,
    _Float16* __restrict__ emb16, float* __restrict__ biasOff,
    _Float16* __restrict__ eWih16, _Float16* __restrict__ dWih16,
    _Float16* __restrict__ dWhh16, _Float16* __restrict__ eWhh16,
    _Float16* __restrict__ sosW16, _Float16* __restrict__ dhtW16,
    float* __restrict__ bias_e, float* __restrict__ bias_d,
    _Float16* __restrict__ emb_in16, float* __restrict__ is_s)
{
    int bx = blockIdx.x, c = threadIdx.x;
    if (bx < 4032){
        int row = bx;
        emb16[(size_t)row*256 + c] = (row < 4000) ? (_Float16)emb[(size_t)row*256 + c] : (_Float16)0.0f;
        if (c == 0) biasOff[row] = (row < 4000) ? (e2v_b[row] - ZSHIFT) : -200.0f;
    } else if (bx < 5056){
        int r = bx - 4032; eWih16[(size_t)r*256 + c] = (_Float16)eWih[(size_t)r*256 + c];
    } else if (bx < 6080){
        int r = bx - 5056; dWih16[(size_t)r*256 + c] = (_Float16)dWih[(size_t)r*256 + c];
    } else if (bx < 7104){
        int r = bx - 6080; dWhh16[(size_t)r*256 + c] = (_Float16)dWhh[(size_t)r*256 + c];
    } else if (bx < 8128){
        int r = bx - 7104; eWhh16[(size_t)r*256 + c] = (_Float16)eWhh[(size_t)r*256 + c];
    } else if (bx < 8384){
        int r = bx - 8128; sosW16[(size_t)r*256 + c] = (_Float16)sosW[(size_t)r*256 + c];
    } else if (bx < 8640){
        int r = bx - 8384; dhtW16[(size_t)r*256 + c] = (_Float16)dhtW[(size_t)r*256 + c];
    } else if (bx < 8644){
        int j = (bx - 8640)*256 + c;
        if (j < 1024){ bias_e[j] = ebih[j]+ebhh[j]; bias_d[j] = dbih[j]+dbhh[j]; }
    } else {
        int ri = bx - 8644;               // < 4096
        int m = ri >> 5, b = ri & 31;
        int tok = x[b*128 + m];
        emb_in16[(size_t)ri*256 + c] = (_Float16)emb[(size_t)tok*256 + c];
        if (c == 0) is_s[ri] = (tok <= 2) ? LOGNEG : 0.0f;
    }
}

// ---------------- standalone GEMM (encoder Xg, gb16) ----------------
__global__ __launch_bounds__(256) void k_gemm16(
    const _Float16* __restrict__ A, const _Float16* __restrict__ W,
    const float* __restrict__ bias, float* __restrict__ C,
    _Float16* __restrict__ C16, int N, int flags)
{
    __shared__ _Float16 Bs[64*264];
    gemm16_body(Bs, threadIdx.x, A, W, bias, C, C16, N, flags,
                blockIdx.y*64, blockIdx.x*64);
}

// ---------------- head GEMMs: sos16 (z=0) + dech0 (z=1) in one launch ----------------
__global__ __launch_bounds__(256) void k_head(
    const _Float16* __restrict__ enc_out16,
    const _Float16* __restrict__ sosW16, const float* __restrict__ sos_b, _Float16* __restrict__ sos16,
    const _Float16* __restrict__ dhtW16, const float* __restrict__ dht_b, _Float16* __restrict__ dech0_16)
{
    __shared__ _Float16 Bs[64*264];
    int z = blockIdx.z;
    gemm16_body(Bs, threadIdx.x, enc_out16,
                z ? dhtW16 : sosW16, z ? dht_b : sos_b, nullptr,
                z ? dech0_16 : sos16, 256,
                z ? (GF_BIAS|GF_TANH|GF_F16OUT) : (GF_BIAS|GF_F16OUT),
                blockIdx.y*64, blockIdx.x*64);
}

// ---------------- encoder LSTM recurrence + fused independent GEMM ----------------
// Blocks 0..31: recurrence (one batch each; weights: 23/32 uint4-slots streamed
// from L2 (compiler remat — accepted, ~376KB/step ≈ 2.3us/step), 9 slots LDS).
// Blocks 32..1055: Xg16dec = emb_in16 @ dWih16^T + bias_d tiles on idle CUs.
// Dyn LDS: 9*1024*16 + 512 + 4096 = 152064 B.
__global__ void __attribute__((amdgpu_flat_work_group_size(512,512), amdgpu_waves_per_eu(2,2)))
k_enc_rnn(
    const _Float16* __restrict__ Xg16, const _Float16* __restrict__ Whh16,
    const float* __restrict__ h0, const float* __restrict__ c0,
    _Float16* __restrict__ enc_out16,
    const _Float16* __restrict__ emb_in16, const _Float16* __restrict__ dWih16,
    const float* __restrict__ bias_d, _Float16* __restrict__ Xg16dec)
{
    extern __shared__ char smem[];
    const int bx = blockIdx.x, tid = threadIdx.x;
    if (bx >= 32){
        int g = bx - 32;                  // < 1024 tiles of 4096x1024
        gemm16_body((_Float16*)smem, tid, emb_in16, dWih16, bias_d,
                    nullptr, Xg16dec, 1024, GF_BIAS|GF_F16OUT,
                    (g >> 4)*64, (g & 15)*64);
        return;
    }
    uint4*  wlds = (uint4*)smem;                   // [9][1024]
    uint32* h_u  = (uint32*)(smem + 147456);       // 128 dwords = 256 f16
    float*  g_s  = (float*)(smem + 147968);        // 1024
    const int b = bx;
    const int r0 = tid, r1 = tid + 512;

    const uint4* p0 = (const uint4*)(Whh16 + (size_t)r0*256);
    const uint4* p1 = (const uint4*)(Whh16 + (size_t)r1*256);
    uint4 w0[23], w1[23];
    #pragma unroll
    for (int i = 0; i < 23; i++){ w0[i] = p0[i]; w1[i] = p1[i]; }
    #pragma unroll
    for (int i = 0; i < 9; i++){
        wlds[i*1024 + r0] = p0[23 + i];
        wlds[i*1024 + r1] = p1[23 + i];
    }
    float c = 0.f;
    if (tid < 256){
        c = c0[tid];
        ((_Float16*)h_u)[tid] = (_Float16)h0[tid];
    }
    __syncthreads();
    const uint4* hu4 = (const uint4*)h_u;

    float xg0 = (float)Xg16[(size_t)b*1024 + r0];
    float xg1 = (float)Xg16[(size_t)b*1024 + r1];
    for (int t = 0; t < 128; t++){
        float nxg0 = 0.f, nxg1 = 0.f;
        if (t < 127){
            nxg0 = (float)Xg16[((size_t)((t+1)*32+b))*1024 + r0];
            nxg1 = (float)Xg16[((size_t)((t+1)*32+b))*1024 + r1];
        }
        float a0 = 0.f, a1 = 0.f;
        #pragma unroll
        for (int i = 0; i < 23; i++){
            uint4 hh = hu4[i];
            a0 = dot2f(w0[i].x, hh.x, a0); a0 = dot2f(w0[i].y, hh.y, a0);
            a0 = dot2f(w0[i].z, hh.z, a0); a0 = dot2f(w0[i].w, hh.w, a0);
            a1 = dot2f(w1[i].x, hh.x, a1); a1 = dot2f(w1[i].y, hh.y, a1);
            a1 = dot2f(w1[i].z, hh.z, a1); a1 = dot2f(w1[i].w, hh.w, a1);
        }
        #pragma unroll
        for (int i = 0; i < 9; i++){
            uint4 hh = hu4[23 + i];
            uint4 v0 = wlds[i*1024 + r0];
            uint4 v1 = wlds[i*1024 + r1];
            a0 = dot2f(v0.x, hh.x, a0); a0 = dot2f(v0.y, hh.y, a0);
            a0 = dot2f(v0.z, hh.z, a0); a0 = dot2f(v0.w, hh.w, a0);
            a1 = dot2f(v1.x, hh.x, a1); a1 = dot2f(v1.y, hh.y, a1);
            a1 = dot2f(v1.z, hh.z, a1); a1 = dot2f(v1.w, hh.w, a1);
        }
        g_s[r0] = a0 + xg0;
        g_s[r1] = a1 + xg1;
        __syncthreads();
        if (tid < 256){
            float gi = g_s[tid], gf = g_s[256+tid], gg = g_s[512+tid], go = g_s[768+tid];
            c = sigmf_(gf)*c + sigmf_(gi)*tanhf(gg);
            float hn = sigmf_(go)*tanhf(c);
            enc_out16[((size_t)(t*32+b))*256 + tid] = (_Float16)(0.5f*hn);
            ((_Float16*)h_u)[tid] = (_Float16)hn;
        }
        __syncthreads();
        xg0 = nxg0; xg1 = nxg1;
    }
}

// ---------------- fused decoder step: 4-gate MFMA + base + LSTM pointwise ----------------
__global__ __launch_bounds__(256) void k_dec_step(
    const _Float16* __restrict__ hprev, const _Float16* __restrict__ dWhh16,
    const _Float16* __restrict__ base16, const float* __restrict__ bias_d,
    float* __restrict__ dec_c, _Float16* __restrict__ dec16_j, int jstep)
{
    __shared__ _Float16 Bs[64*264];
    int tid = threadIdx.x;
    int wave = tid >> 6, lane = tid & 63;
    int ln = lane & 15, quad = lane >> 4;
    int u0 = blockIdx.x * 64, r0 = blockIdx.y * 64;

    half8_t a[8];
    const half8_t* Ap = (const half8_t*)(hprev + (size_t)(r0 + wave*16 + ln)*256 + quad*8);
    #pragma unroll
    for (int ks = 0; ks < 8; ks++) a[ks] = Ap[ks*4];

    f32x4_t cg[4][4];
    #pragma unroll
    for (int g = 0; g < 4; g++){
        __syncthreads();
        #pragma unroll
        for (int i = 0; i < 8; i++){
            int idx = i*256 + tid;
            int row = idx >> 5, c16 = idx & 31;
            *(uint4*)&Bs[row*264 + c16*8] =
                *(const uint4*)(dWhh16 + (size_t)(g*256 + u0 + row)*256 + c16*8);
        }
        __syncthreads();
        #pragma unroll
        for (int ct = 0; ct < 4; ct++){
            f32x4_t c4 = {0.f,0.f,0.f,0.f};
            const _Float16* bp = &Bs[(ct*16+ln)*264 + quad*8];
            #pragma unroll
            for (int ks = 0; ks < 8; ks++){
                half8_t b = *(const half8_t*)(bp + ks*32);
                c4 = __builtin_amdgcn_mfma_f32_16x16x32_f16(a[ks], b, c4, 0, 0, 0);
            }
            cg[g][ct] = c4;
        }
    }
    #pragma unroll
    for (int ct = 0; ct < 4; ct++){
        int u = u0 + ct*16 + ln;
        #pragma unroll
        for (int reg = 0; reg < 4; reg++){
            int r = r0 + wave*16 + quad*4 + reg;
            float bi, bf, bg, bo;
            if (jstep == 0){
                const _Float16* bp = base16 + (size_t)r*1024 + u;
                bi = (float)bp[0]; bf = (float)bp[256]; bg = (float)bp[512]; bo = (float)bp[768];
            } else {
                int s = r >> 5, b_ = r & 31;
                int m = s + jstep;
                if (m < 128){
                    const _Float16* bp = base16 + (size_t)(m*32+b_)*1024 + u;
                    bi = (float)bp[0]; bf = (float)bp[256]; bg = (float)bp[512]; bo = (float)bp[768];
                } else {
                    bi = bias_d[u]; bf = bias_d[256+u]; bg = bias_d[512+u]; bo = bias_d[768+u];
                }
            }
            float gi = cg[0][ct][reg] + bi;
            float gf = cg[1][ct][reg] + bf;
            float gg = cg[2][ct][reg] + bg;
            float go = cg[3][ct][reg] + bo;
            float cv = (jstep == 0) ? 0.0f : dec_c[(size_t)r*256 + u];
            cv = sigmf_(gf)*cv + sigmf_(gi)*tanhf(gg);
            float hv = sigmf_(go)*tanhf(cv);
            dec_c[(size_t)r*256 + u] = cv;
            dec16_j[(size_t)r*256 + u] = (_Float16)hv;
        }
    }
}

// ---------------- logits: 4 vocab quarters, fused exp-sum + tgt/EOS extraction ----------------
// grid (315, 4). Quarter q covers vocab tiles [q*16, q==3?63:q*16+16) (1024-col-aligned).
// Writes ps[q][r] (partial exp-sum), pzt[q][r] (z[tgt] if tgt in quarter), pze[q][r].
__global__ __launch_bounds__(256) void k_logits(
    const _Float16* __restrict__ dec16, const _Float16* __restrict__ emb16,
    const float* __restrict__ biasOff, const int* __restrict__ x,
    float* __restrict__ ps, float* __restrict__ pzt, float* __restrict__ pze)
{
    __shared__ _Float16 Bs[64*264];
    __shared__ int tgt_s[64];
    int tid = threadIdx.x;
    int wave = tid >> 6, lane = tid & 63;
    int ln = lane & 15, quad = lane >> 4;
    int r0 = blockIdx.x * 64;
    int q = blockIdx.y;
    int vt0 = q*16, vt1 = (q == 3) ? 63 : (vt0 + 16);

    if (tid < 64){
        int r = r0 + tid;
        int t = r / 4032, sb = r % 4032;
        int s_ = sb >> 5, b = sb & 31;
        int m = s_ + 1 + t;
        tgt_s[tid] = (m < 128) ? x[b*128 + m] : 0;
    }
    half8_t a[8];
    const half8_t* Ap = (const half8_t*)(dec16 + (size_t)(r0 + wave*16 + ln)*256 + quad*8);
    #pragma unroll
    for (int ks = 0; ks < 8; ks++) a[ks] = Ap[ks*4];
    __syncthreads();
    int tg[4];
    #pragma unroll
    for (int reg = 0; reg < 4; reg++) tg[reg] = tgt_s[wave*16 + quad*4 + reg];

    float s[4]   = {0.f,0.f,0.f,0.f};
    float rzt[4] = {-1e30f,-1e30f,-1e30f,-1e30f};
    float rze[4] = {-1e30f,-1e30f,-1e30f,-1e30f};

    for (int vt = vt0; vt < vt1; vt++){
        int v0 = vt*64;
        __syncthreads();
        #pragma unroll
        for (int i = 0; i < 8; i++){
            int idx = i*256 + tid;
            int row = idx >> 5, c16 = idx & 31;
            *(uint4*)&Bs[row*264 + c16*8] =
                *(const uint4*)(emb16 + (size_t)(v0+row)*256 + c16*8);
        }
        __syncthreads();

        #pragma unroll
        for (int ct = 0; ct < 4; ct++){
            f32x4_t c4 = {0.f,0.f,0.f,0.f};
            const _Float16* bp = &Bs[(ct*16+ln)*264 + quad*8];
            #pragma unroll
            for (int ks = 0; ks < 8; ks++){
                half8_t b = *(const half8_t*)(bp + ks*32);
                c4 = __builtin_amdgcn_mfma_f32_16x16x32_f16(a[ks], b, c4, 0, 0, 0);
            }
            int v = v0 + ct*16 + ln;
            float bb = biasOff[v];
            #pragma unroll
            for (int reg = 0; reg < 4; reg++){
                float z = c4[reg] + bb;
                s[reg] += __expf(z);
                if (v == tg[reg]) rzt[reg] = z;
                if (v == 3)       rze[reg] = z;
            }
        }
    }
    // reduce across the 16 ln lanes of each quad (sum / max)
    #pragma unroll
    for (int reg = 0; reg < 4; reg++){
        float vsum = s[reg], vzt = rzt[reg], vze = rze[reg];
        #pragma unroll
        for (int off = 1; off < 16; off <<= 1){
            vsum += __shfl_xor(vsum, off, 64);
            vzt = fmaxf(vzt, __shfl_xor(vzt, off, 64));
            vze = fmaxf(vze, __shfl_xor(vze, off, 64));
        }
        s[reg] = vsum; rzt[reg] = vzt; rze[reg] = vze;
    }
    if (ln == 0){
        #pragma unroll
        for (int reg = 0; reg < 4; reg++){
            int r = r0 + wave*16 + quad*4 + reg;
            ps [q*20160 + r] = s[reg];
            pzt[q*20160 + r] = rzt[reg];
            pze[q*20160 + r] = rze[reg];
        }
    }
}

// ---------------- combine quarters -> tlp / eosb ----------------
__global__ __launch_bounds__(256) void k_combine(
    const float* __restrict__ ps, const float* __restrict__ pzt,
    const float* __restrict__ pze, const int* __restrict__ x,
    float* __restrict__ tlp, float* __restrict__ eosb)
{
    int r = blockIdx.x*256 + threadIdx.x;
    if (r >= 20160) return;
    float lse = __logf(ps[r] + ps[20160+r] + ps[2*20160+r] + ps[3*20160+r]);
    int t = r / 4032, sb = r % 4032;
    int s_ = sb >> 5, b = sb & 31;
    int m = s_ + 1 + t;
    int tg = (m < 128) ? x[b*128 + m] : 0;
    float zt = pzt[(tg >> 10)*20160 + r];   // quarters are 1024-col aligned
    float ze = pze[r];                      // EOS=3 -> quarter 0
    if (t < 4)  tlp[(t*126+s_)*32 + b]      = zt - lse;
    if (t >= 1) eosb[((t-1)*126+s_)*32 + b] = ze - lse;
}

// ---------------- segmental DP + final reduction ----------------
__global__ __launch_bounds__(128) void k_finalize(
    const float* __restrict__ tlp, const float* __restrict__ eosb,
    const float* __restrict__ is_s, const int* __restrict__ lengths,
    float* __restrict__ seg_g, float* __restrict__ out)
{
    int tid = threadIdx.x;
    int k = tid >> 5, b = tid & 31;
    for (int s = 0; s < 126; s++){
        float cum = 0.f;
        for (int kk = 0; kk <= k; kk++) cum += tlp[(kk*126+s)*32 + b];
        if (k >= 1){
            for (int kk = 1; kk <= k; kk++){
                int m = s+1+kk;
                if (m < 128) cum += is_s[m*32+b];
            }
            cum += is_s[(s+1)*32 + b];
        }
        float lp = cum + eosb[(k*126+s)*32 + b];
        int jl = min(4, 126 - s);
        if (k >= jl) lp = LOGNEG;
        seg_g[(s*4+k)*32 + b] = lp;
    }
    __threadfence_block();
    __syncthreads();
    __shared__ float nll_s[32];
    if (tid < 32){
        int target = lengths[tid] - 2;
        float b0 = 0.f, b1 = LOGNEG, b2 = LOGNEG, b3 = LOGNEG;
        float nllb = 0.f;
        for (int e = 1; e <= 126; e++){
            float v0 = b0 + seg_g[((e-1)*4+0)*32 + tid];
            float v1 = b1 + ((e >= 2) ? seg_g[((e-2)*4+1)*32 + tid] : LOGNEG);
            float v2 = b2 + ((e >= 3) ? seg_g[((e-3)*4+2)*32 + tid] : LOGNEG);
            float v3 = b3 + ((e >= 4) ? seg_g[((e-4)*4+3)*32 + tid] : LOGNEG);
            float mx = fmaxf(fmaxf(v0,v1), fmaxf(v2,v3));
            float a = mx + logf(expf(v0-mx)+expf(v1-mx)+expf(v2-mx)+expf(v3-mx));
            if (e == target) nllb = -a;
            b3 = b2; b2 = b1; b1 = b0; b0 = a;
        }
        nll_s[tid] = nllb;
    }
    __syncthreads();
    if (tid == 0){
        float tot = 0.f; int lsum = 0;
        for (int i = 0; i < 32; i++){ tot += nll_s[i]; lsum += lengths[i]; }
        out[0] = tot / (float)(lsum - 64);
    }
}

extern "C" void kernel_launch(void* const* d_in, const int* in_sizes, int n_in,
                              void* d_out, int out_size, void* d_ws, size_t ws_size,
                              hipStream_t stream)
{
    const int*   x        = (const int*)  d_in[0];
    const int*   lengths  = (const int*)  d_in[1];
    const float* emb      = (const float*)d_in[2];
    const float* e2v_b    = (const float*)d_in[3];
    const float* enc_Wih  = (const float*)d_in[4];
    const float* enc_Whh  = (const float*)d_in[5];
    const float* enc_bih  = (const float*)d_in[6];
    const float* enc_bhh  = (const float*)d_in[7];
    const float* enc_h0   = (const float*)d_in[8];
    const float* enc_c0   = (const float*)d_in[9];
    const float* dec_Wih  = (const float*)d_in[10];
    const float* dec_Whh  = (const float*)d_in[11];
    const float* dec_bih  = (const float*)d_in[12];
    const float* dec_bhh  = (const float*)d_in[13];
    const float* dht_W    = (const float*)d_in[14];
    const float* dht_b    = (const float*)d_in[15];
    const float* sos_W    = (const float*)d_in[16];
    const float* sos_b    = (const float*)d_in[17];
    float* out = (float*)d_out;

    char* wsb = (char*)d_ws;
    size_t off = 0;
    auto alloc = [&](size_t bytes)->void*{
        void* p = (void*)(wsb + off);
        off += ((bytes + 255)/256)*256;
        return p;
    };
    _Float16* emb_in16 = (_Float16*)alloc((size_t)4096*256*2);
    float*    is_s     = (float*)alloc(4096*4);
    _Float16* XgE16    = (_Float16*)alloc((size_t)4096*1024*2);
    _Float16* Xg16     = (_Float16*)alloc((size_t)4096*1024*2);
    _Float16* gb16     = (_Float16*)alloc((size_t)4032*1024*2);
    _Float16* enc_out16= (_Float16*)alloc((size_t)4096*256*2);
    _Float16* sos16    = (_Float16*)alloc((size_t)4032*256*2);
    _Float16* dech0_16 = (_Float16*)alloc((size_t)4032*256*2);
    float*    dec_c    = (float*)alloc((size_t)4032*256*4);
    _Float16* dec16    = (_Float16*)alloc((size_t)5*4032*256*2);
    float*    bias_e   = (float*)alloc(1024*4);
    float*    bias_d   = (float*)alloc(1024*4);
    _Float16* emb16    = (_Float16*)alloc((size_t)4032*256*2);
    float*    biasOff  = (float*)alloc(4032*4);
    float*    ps       = (float*)alloc((size_t)4*20160*4);
    float*    pzt      = (float*)alloc((size_t)4*20160*4);
    float*    pze      = (float*)alloc((size_t)4*20160*4);
    float*    tlp      = (float*)alloc((size_t)4*126*32*4);
    float*    eosb     = (float*)alloc((size_t)4*126*32*4);
    float*    seg_g    = (float*)alloc((size_t)126*4*32*4);
    _Float16* eWih16   = (_Float16*)alloc((size_t)1024*256*2);
    _Float16* dWih16   = (_Float16*)alloc((size_t)1024*256*2);
    _Float16* dWhh16   = (_Float16*)alloc((size_t)1024*256*2);
    _Float16* eWhh16   = (_Float16*)alloc((size_t)1024*256*2);
    _Float16* sosW16   = (_Float16*)alloc((size_t)256*256*2);
    _Float16* dhtW16   = (_Float16*)alloc((size_t)256*256*2);
    (void)ws_size; (void)in_sizes; (void)n_in; (void)out_size;

    hipFuncSetAttribute(reinterpret_cast<const void*>(k_enc_rnn),
                        hipFuncAttributeMaxDynamicSharedMemorySize, 152064);

    // 1. fused prep (f16 packs + bias sums + embed gather)
    k_prep_pack<<<12740, 256, 0, stream>>>(x, emb, e2v_b, enc_Wih, dec_Wih, dec_Whh, enc_Whh,
        sos_W, dht_W, enc_bih, enc_bhh, dec_bih, dec_bhh,
        emb16, biasOff, eWih16, dWih16, dWhh16, eWhh16, sosW16, dhtW16, bias_e, bias_d,
        emb_in16, is_s);
    // 2. encoder input-side gates (f16 out)
    k_gemm16<<<dim3(16,64), 256, 0, stream>>>(emb_in16, eWih16, bias_e, nullptr, XgE16,
        1024, GF_BIAS|GF_F16OUT);
    // 3. encoder recurrence + fused decoder input-gate GEMM (on idle CUs)
    k_enc_rnn<<<32 + 1024, 512, 152064, stream>>>(XgE16, eWhh16, enc_h0, enc_c0, enc_out16,
        emb_in16, dWih16, bias_d, Xg16);
    // 4. head GEMMs: sos16 + dech0_16 in one launch
    k_head<<<dim3(4,63,2), 256, 0, stream>>>(enc_out16, sosW16, sos_b, sos16,
        dhtW16, dht_b, dech0_16);
    // 5. gb16 = sos16 @ dWih16^T + bias_d (f16)
    k_gemm16<<<dim3(16,63), 256, 0, stream>>>(sos16, dWih16, bias_d, nullptr, gb16,
        1024, GF_BIAS|GF_F16OUT);
    // 6. decoder recurrence: 5 fused steps
    for (int j = 0; j < 5; j++){
        const _Float16* hA = (j == 0) ? dech0_16 : (dec16 + (size_t)(j-1)*4032*256);
        const _Float16* base = (j == 0) ? gb16 : Xg16;
        k_dec_step<<<dim3(4,63), 256, 0, stream>>>(hA, dWhh16, base, bias_d,
            dec_c, dec16 + (size_t)j*4032*256, j);
    }
    // 7. logits: 4 vocab quarters, fused exp-sum + tgt/EOS extraction
    k_logits<<<dim3(315,4), 256, 0, stream>>>(dec16, emb16, biasOff, x, ps, pzt, pze);
    // 8. combine quarters
    k_combine<<<79, 256, 0, stream>>>(ps, pzt, pze, x, tlp, eosb);
    // 9. segmental DP + reduction
    k_finalize<<<1, 128, 0, stream>>>(tlp, eosb, is_s, lengths, seg_g, out);
}